// Round 1
// baseline (337.050 us; speedup 1.0000x reference)
//
#include <hip/hip_runtime.h>

#define BB 16
#define CC 64
#define FD 64
#define TD 64
#define ICC 32
#define NN 4096   // F*T
#define MM 1024   // 32*32

// ---------------- K1: a[b,n] = dot(v_th, x[b,:,n]) + s_th + pos ----------------
__global__ void k_a(const float* __restrict__ x, const float* __restrict__ theta_w,
                    const float* __restrict__ theta_b, const float* __restrict__ concat_w,
                    float* __restrict__ a_buf) {
    __shared__ float v_th[CC];
    __shared__ float s_const;
    int b = blockIdx.x;
    int tid = threadIdx.x;
    if (tid < CC) {
        float s = 0.f;
        for (int ic = 0; ic < ICC; ++ic) s += concat_w[ic] * theta_w[ic * CC + tid];
        v_th[tid] = s;
    }
    if (tid == 0) {
        float s = 0.f;
        for (int ic = 0; ic < ICC; ++ic) s += concat_w[ic] * theta_b[ic];
        s_const = s;
    }
    __syncthreads();
    float wd0 = concat_w[2 * ICC], wd1 = concat_w[2 * ICC + 1];
    const float* xb = x + (size_t)b * CC * NN;
    for (int n = tid; n < NN; n += blockDim.x) {
        float s = 0.f;
        #pragma unroll 8
        for (int c = 0; c < CC; ++c) s += v_th[c] * xb[c * NN + n];
        int f = n >> 6, t = n & 63;
        float fg = f * (1.0f / 63.0f), tg = t * (1.0f / 63.0f);
        a_buf[b * NN + n] = s + s_const + wd0 * fg + wd1 * tg;
    }
}

// ---------------- K2: psi/phi conv + 2x2 maxpool; psiT[b][m][ic]; c_buf[b][m] ----------------
__global__ void k_pool(const float* __restrict__ x,
                       const float* __restrict__ psi_w, const float* __restrict__ psi_b,
                       const float* __restrict__ phi_w, const float* __restrict__ phi_b,
                       const float* __restrict__ concat_w,
                       float* __restrict__ psiT, float* __restrict__ c_buf) {
    // grid: B*128 blocks, 256 threads. Each block: 8 m-values x 32 ic.
    __shared__ float pw[CC * ICC];  // transposed [c][ic]
    __shared__ float fw[CC * ICC];
    int tid = threadIdx.x;
    int b = blockIdx.x >> 7;
    int mblk = blockIdx.x & 127;
    for (int i = tid; i < CC * ICC; i += 256) {
        int ic = i >> 6, c = i & 63;   // i = ic*64 + c
        pw[c * ICC + ic] = psi_w[i];
        fw[c * ICC + ic] = phi_w[i];
    }
    __syncthreads();
    int ic = tid & 31;
    int m = mblk * 8 + (tid >> 5);
    int fp = m >> 5, tp = m & 31;
    const float* xb = x + (size_t)b * CC * NN + (fp * 2) * TD + tp * 2;
    float ps0 = 0, ps1 = 0, ps2 = 0, ps3 = 0;
    float ph0 = 0, ph1 = 0, ph2 = 0, ph3 = 0;
    for (int c = 0; c < CC; ++c) {
        const float* p = xb + c * NN;
        float x00 = p[0], x01 = p[1], x10 = p[TD], x11 = p[TD + 1];
        float wp = pw[c * ICC + ic], wf = fw[c * ICC + ic];
        ps0 += wp * x00; ps1 += wp * x01; ps2 += wp * x10; ps3 += wp * x11;
        ph0 += wf * x00; ph1 += wf * x01; ph2 += wf * x10; ph3 += wf * x11;
    }
    float psi_val = fmaxf(fmaxf(ps0, ps1), fmaxf(ps2, ps3)) + psi_b[ic];
    float phi_val = fmaxf(fmaxf(ph0, ph1), fmaxf(ph2, ph3)) + phi_b[ic];
    psiT[((size_t)b * MM + m) * ICC + ic] = psi_val;
    float v = concat_w[ICC + ic] * phi_val;
    for (int off = 16; off >= 1; off >>= 1) v += __shfl_xor(v, off, 32);
    if (ic == 0) {
        float wd0 = concat_w[2 * ICC], wd1 = concat_w[2 * ICC + 1];
        float fg = fp * (1.0f / 31.0f), tg = tp * (1.0f / 31.0f);
        c_buf[b * MM + m] = v - (wd0 * fg + wd1 * tg);
    }
}

// ---------------- K3: attention matmul + output conv -> wy ----------------
__global__ void __launch_bounds__(256) k_attn(
        const float* __restrict__ a_buf, const float* __restrict__ c_buf,
        const float* __restrict__ psiT,
        const float* __restrict__ W_w, const float* __restrict__ W_b,
        float* __restrict__ wy) {
    // grid: B*16 blocks; 256 threads; block handles n-tile of 256 for one batch.
    __shared__ float c_lds[MM];          // 4 KB
    __shared__ float psi_lds[256 * ICC]; // 32 KB
    __shared__ float W_lds[CC * ICC];    // 8 KB, layout [o][ic]
    int tid = threadIdx.x;
    int b = blockIdx.x >> 4;
    int ntile = blockIdx.x & 15;
    for (int i = tid; i < MM; i += 256) c_lds[i] = c_buf[b * MM + i];
    for (int i = tid; i < CC * ICC; i += 256) {
        int o = i >> 5, icc = i & 31;
        W_lds[i] = W_w[o * (ICC + 1) + icc];   // channel 32 multiplies zeros -> skipped
    }
    int n = ntile * 256 + tid;
    float a_n = a_buf[b * NN + n];
    float acc[ICC];
    #pragma unroll
    for (int i = 0; i < ICC; ++i) acc[i] = 0.f;
    for (int mc = 0; mc < MM; mc += 256) {
        __syncthreads();
        const float* src = psiT + ((size_t)b * MM + mc) * ICC;
        for (int i = tid; i < 256 * ICC; i += 256) psi_lds[i] = src[i];
        __syncthreads();
        for (int j = 0; j < 256; ++j) {
            float f = fmaxf(a_n + c_lds[mc + j], 0.f);
            const float4* p4 = (const float4*)(psi_lds + j * ICC);
            #pragma unroll
            for (int q = 0; q < ICC / 4; ++q) {
                float4 p = p4[q];
                acc[q * 4 + 0] += f * p.x; acc[q * 4 + 1] += f * p.y;
                acc[q * 4 + 2] += f * p.z; acc[q * 4 + 3] += f * p.w;
            }
        }
    }
    float inv_w = 1.0f / (float)MM;
    #pragma unroll
    for (int i = 0; i < ICC; ++i) acc[i] *= inv_w;
    float* wyb = wy + (size_t)b * CC * NN + n;
    for (int o = 0; o < CC; ++o) {
        float s = W_b[o];
        const float4* w4 = (const float4*)(W_lds + o * ICC);
        #pragma unroll
        for (int q = 0; q < ICC / 4; ++q) {
            float4 wv = w4[q];
            s += wv.x * acc[q * 4 + 0] + wv.y * acc[q * 4 + 1]
               + wv.z * acc[q * 4 + 2] + wv.w * acc[q * 4 + 3];
        }
        wyb[o * NN] = s;   // coalesced across threads (n contiguous)
    }
}

// ---------------- K4: BN statistics per output channel ----------------
__global__ void k_stats(const float* __restrict__ wy, const float* __restrict__ bn_gamma,
                        const float* __restrict__ bn_beta, float* __restrict__ scale_shift) {
    int o = blockIdx.x;
    int tid = threadIdx.x;
    float s = 0.f, s2 = 0.f;
    for (int b = 0; b < BB; ++b) {
        const float* p = wy + (size_t)b * CC * NN + (size_t)o * NN;
        for (int n = tid; n < NN; n += 256) {
            float v = p[n];
            s += v; s2 += v * v;
        }
    }
    for (int off = 32; off >= 1; off >>= 1) {
        s  += __shfl_xor(s, off, 64);
        s2 += __shfl_xor(s2, off, 64);
    }
    __shared__ float ws1[4], ws2[4];
    int wid = tid >> 6, lane = tid & 63;
    if (lane == 0) { ws1[wid] = s; ws2[wid] = s2; }
    __syncthreads();
    if (tid == 0) {
        float S = ws1[0] + ws1[1] + ws1[2] + ws1[3];
        float S2 = ws2[0] + ws2[1] + ws2[2] + ws2[3];
        float nN = (float)(BB * NN);
        float mean = S / nN;
        float var = S2 / nN - mean * mean;
        float rstd = rsqrtf(var + 1e-5f);
        float sc = bn_gamma[o] * rstd;
        scale_shift[o] = sc;
        scale_shift[CC + o] = bn_beta[o] - mean * sc;
    }
}

// ---------------- K5: normalize + residual (in-place on d_out) ----------------
__global__ void k_final(float* __restrict__ out, const float* __restrict__ x,
                        const float* __restrict__ scale_shift) {
    size_t i = (size_t)blockIdx.x * blockDim.x + threadIdx.x;
    size_t tot = (size_t)BB * CC * NN / 4;
    if (i < tot) {
        float4 w4 = ((const float4*)out)[i];
        float4 x4 = ((const float4*)x)[i];
        int o = (int)(((i * 4) >> 12) & 63);
        float sc = scale_shift[o], sh = scale_shift[CC + o];
        float4 r;
        r.x = w4.x * sc + sh + x4.x;
        r.y = w4.y * sc + sh + x4.y;
        r.z = w4.z * sc + sh + x4.z;
        r.w = w4.w * sc + sh + x4.w;
        ((float4*)out)[i] = r;
    }
}

extern "C" void kernel_launch(void* const* d_in, const int* in_sizes, int n_in,
                              void* d_out, int out_size, void* d_ws, size_t ws_size,
                              hipStream_t stream) {
    const float* x        = (const float*)d_in[0];
    const float* psi_w    = (const float*)d_in[1];
    const float* psi_b    = (const float*)d_in[2];
    const float* theta_w  = (const float*)d_in[3];
    const float* theta_b  = (const float*)d_in[4];
    const float* phi_w    = (const float*)d_in[5];
    const float* phi_b    = (const float*)d_in[6];
    const float* concat_w = (const float*)d_in[7];
    const float* W_w      = (const float*)d_in[8];
    const float* W_b      = (const float*)d_in[9];
    const float* bn_gamma = (const float*)d_in[10];
    const float* bn_beta  = (const float*)d_in[11];

    float* ws = (float*)d_ws;
    float* a_buf  = ws;                         // B*N      = 65536
    float* c_buf  = a_buf + BB * NN;            // B*M      = 16384
    float* psiT   = c_buf + BB * MM;            // B*M*IC   = 524288
    float* sc_sh  = psiT + (size_t)BB * MM * ICC; // 128
    float* wy = (float*)d_out;                  // staged in output buffer

    k_a<<<BB, 256, 0, stream>>>(x, theta_w, theta_b, concat_w, a_buf);
    k_pool<<<BB * 128, 256, 0, stream>>>(x, psi_w, psi_b, phi_w, phi_b, concat_w, psiT, c_buf);
    k_attn<<<BB * 16, 256, 0, stream>>>(a_buf, c_buf, psiT, W_w, W_b, wy);
    k_stats<<<CC, 256, 0, stream>>>(wy, bn_gamma, bn_beta, sc_sh);
    k_final<<<(BB * CC * NN / 4 + 255) / 256, 256, 0, stream>>>(wy, x, sc_sh);
}

// Round 4
// 140.362 us; speedup vs baseline: 2.4013x; 2.4013x over previous
//
#include <hip/hip_runtime.h>

#define BB 16
#define CC 64
#define ICC 32
#define NN 4096   // F*T
#define MM 1024   // 32*32

typedef __attribute__((ext_vector_type(8))) short short8;
typedef __attribute__((ext_vector_type(4))) float f32x4;

static __device__ __forceinline__ unsigned cvt_pk_bf16(float lo, float hi) {
    unsigned d;
    asm("v_cvt_pk_bf16_f32 %0, %1, %2" : "=v"(d) : "v"(lo), "v"(hi));
    return d;
}
static __device__ __forceinline__ short8 as_s8(uint4 u) {
    union { uint4 a; short8 b; } t; t.a = u; return t.b;
}

// ---- K1: psi/phi conv + 2x2 maxpool (thread-local m-pair) + a_buf + c_buf ----
__global__ void __launch_bounds__(256) k_pool(
        const float* __restrict__ x,
        const float* __restrict__ psi_w, const float* __restrict__ psi_b,
        const float* __restrict__ phi_w, const float* __restrict__ phi_b,
        const float* __restrict__ theta_w, const float* __restrict__ theta_b,
        const float* __restrict__ concat_w,
        unsigned* __restrict__ psi_pk, float* __restrict__ c_buf,
        float* __restrict__ a_buf, float* __restrict__ sumbuf) {
    __shared__ float pw[CC * ICC];   // [c][ic]
    __shared__ float fw[CC * ICC];
    __shared__ float vth[CC];
    __shared__ float xt[CC * 64];    // [c][row2][32]
    __shared__ float sconst;
    int tid = threadIdx.x;
    int b = blockIdx.x >> 6;
    int mtile = blockIdx.x & 63;     // 16 m-values per block
    int fp = mtile >> 1;             // pooled row (same for all 16 m)
    int tpb = (mtile & 1) * 16;      // pooled col base

    if (blockIdx.x == 0 && tid < 2 * CC) sumbuf[tid] = 0.f;
    for (int i = tid; i < CC * ICC; i += 256) {
        int ic = i >> 6, c = i & 63;
        pw[c * ICC + ic] = psi_w[i];
        fw[c * ICC + ic] = phi_w[i];
    }
    if (tid < CC) {
        float s = 0.f;
        for (int ic = 0; ic < ICC; ++ic) s += concat_w[ic] * theta_w[ic * CC + tid];
        vth[tid] = s;
    }
    if (tid == 255) {
        float s = 0.f;
        for (int ic = 0; ic < ICC; ++ic) s += concat_w[ic] * theta_b[ic];
        sconst = s;
    }
    // stage x tile: 64 c x 2 rows x 32 cols
    const float* xb = x + (size_t)b * CC * NN;
    for (int i = tid; i < 1024; i += 256) {
        int c = i >> 4, row = (i >> 3) & 1, jj = i & 7;
        float4 v = *(const float4*)(xb + c * NN + (2 * fp + row) * 64 + 2 * tpb + jj * 4);
        *(float4*)&xt[c * 64 + row * 32 + jj * 4] = v;
    }
    __syncthreads();

    int ic = tid & 31;
    int mp = tid >> 5;               // m-pair index 0..7 -> m0 = mtile*16 + 2*mp
    float p00=0,p01=0,p02=0,p03=0, p10=0,p11=0,p12=0,p13=0;
    float q00=0,q01=0,q02=0,q03=0, q10=0,q11=0,q12=0,q13=0;
    for (int c = 0; c < CC; ++c) {
        float4 r0 = *(const float4*)&xt[c * 64 + mp * 4];        // row 0, cols 4mp..4mp+3
        float4 r1 = *(const float4*)&xt[c * 64 + 32 + mp * 4];   // row 1
        float wp = pw[c * ICC + ic], wf = fw[c * ICC + ic];
        p00 += wp*r0.x; p01 += wp*r0.y; p02 += wp*r1.x; p03 += wp*r1.y;
        p10 += wp*r0.z; p11 += wp*r0.w; p12 += wp*r1.z; p13 += wp*r1.w;
        q00 += wf*r0.x; q01 += wf*r0.y; q02 += wf*r1.x; q03 += wf*r1.y;
        q10 += wf*r0.z; q11 += wf*r0.w; q12 += wf*r1.z; q13 += wf*r1.w;
    }
    float pb = psi_b[ic], fb = phi_b[ic];
    float psi0 = fmaxf(fmaxf(p00,p01),fmaxf(p02,p03)) + pb;
    float psi1 = fmaxf(fmaxf(p10,p11),fmaxf(p12,p13)) + pb;
    float phi0 = fmaxf(fmaxf(q00,q01),fmaxf(q02,q03)) + fb;
    float phi1 = fmaxf(fmaxf(q10,q11),fmaxf(q12,q13)) + fb;

    int m0 = mtile * 16 + 2 * mp;
    float wd0 = concat_w[2 * ICC], wd1 = concat_w[2 * ICC + 1];
    float wph = concat_w[ICC + ic];
    float v0 = wph * phi0, v1 = wph * phi1;
    for (int off = 16; off >= 1; off >>= 1) {
        v0 += __shfl_xor(v0, off, 32);
        v1 += __shfl_xor(v1, off, 32);
    }
    if (ic == 0) {
        int tp = tpb + 2 * mp;
        c_buf[b * MM + m0]     = v0 - (wd0 * (fp * (1.f/31.f)) + wd1 * (tp * (1.f/31.f)));
        c_buf[b * MM + m0 + 1] = v1 - (wd0 * (fp * (1.f/31.f)) + wd1 * ((tp + 1) * (1.f/31.f)));
    }
    // psi bf16 pair, MFMA-B fragment order (thread-local pack, no shfl)
    int mpg = mtile * 8 + mp;                 // global m-pair 0..511
    int ks = mpg >> 4, kg = (mpg >> 2) & 3, cidx = mpg & 3;
    psi_pk[b * 16384 + ks * 512 + (ic >> 4) * 256 + kg * 64 + (ic & 15) * 4 + cidx]
        = cvt_pk_bf16(psi0, psi1);

    // a_buf: 64 pixels per block, threads with ic<8
    if (ic < 8) {
        int pix = mp * 8 + ic;
        int row = pix >> 5, colo = pix & 31;
        float sa = 0.f;
        #pragma unroll 8
        for (int c = 0; c < CC; ++c) sa += vth[c] * xt[c * 64 + row * 32 + colo];
        int f = 2 * fp + row, t = 2 * tpb + colo;
        a_buf[b * NN + f * 64 + t] = sa + sconst + wd0 * (f * (1.f/63.f)) + wd1 * (t * (1.f/63.f));
    }
}

static __device__ __forceinline__ void mfma_step(
        int ks, const float* c_lds, int hi4, float a0, float a1,
        uint4 bu0, uint4 bu1,
        f32x4& acc00, f32x4& acc01, f32x4& acc10, f32x4& acc11) {
    float4 c0 = *(const float4*)&c_lds[ks * 32 + hi4 * 8];
    float4 c1 = *(const float4*)&c_lds[ks * 32 + hi4 * 8 + 4];
    uint4 up;
    up.x = cvt_pk_bf16(fmaxf(a0 + c0.x, 0.f), fmaxf(a0 + c0.y, 0.f));
    up.y = cvt_pk_bf16(fmaxf(a0 + c0.z, 0.f), fmaxf(a0 + c0.w, 0.f));
    up.z = cvt_pk_bf16(fmaxf(a0 + c1.x, 0.f), fmaxf(a0 + c1.y, 0.f));
    up.w = cvt_pk_bf16(fmaxf(a0 + c1.z, 0.f), fmaxf(a0 + c1.w, 0.f));
    short8 ua0 = as_s8(up);
    up.x = cvt_pk_bf16(fmaxf(a1 + c0.x, 0.f), fmaxf(a1 + c0.y, 0.f));
    up.y = cvt_pk_bf16(fmaxf(a1 + c0.z, 0.f), fmaxf(a1 + c0.w, 0.f));
    up.z = cvt_pk_bf16(fmaxf(a1 + c1.x, 0.f), fmaxf(a1 + c1.y, 0.f));
    up.w = cvt_pk_bf16(fmaxf(a1 + c1.z, 0.f), fmaxf(a1 + c1.w, 0.f));
    short8 ua1 = as_s8(up);
    short8 vb0 = as_s8(bu0), vb1 = as_s8(bu1);
    acc00 = __builtin_amdgcn_mfma_f32_16x16x32_bf16(ua0, vb0, acc00, 0, 0, 0);
    acc01 = __builtin_amdgcn_mfma_f32_16x16x32_bf16(ua0, vb1, acc01, 0, 0, 0);
    acc10 = __builtin_amdgcn_mfma_f32_16x16x32_bf16(ua1, vb0, acc10, 0, 0, 0);
    acc11 = __builtin_amdgcn_mfma_f32_16x16x32_bf16(ua1, vb1, acc11, 0, 0, 0);
}

// ---- K2: MFMA attention + output conv -> wy ----
__global__ void __launch_bounds__(256) k_attn(
        const float* __restrict__ a_buf, const float* __restrict__ c_buf,
        const unsigned* __restrict__ psi_pk,
        const float* __restrict__ W_w, const float* __restrict__ W_b,
        float* __restrict__ wy) {
    __shared__ float c_lds[MM];          // 4 KB
    __shared__ float W_lds[CC * ICC];    // 8 KB [o][ic]
    __shared__ float Wb_lds[CC];
    __shared__ float yT[ICC * 130];      // transposed y, padded: 16.6 KB
    int tid = threadIdx.x;
    int b = blockIdx.x >> 5;
    int ntile = blockIdx.x & 31;         // 128 pixels per block
    for (int i = tid; i < MM; i += 256) c_lds[i] = c_buf[b * MM + i];
    for (int i = tid; i < CC * ICC; i += 256) W_lds[i] = W_w[(i >> 5) * (ICC + 1) + (i & 31)];
    if (tid < CC) Wb_lds[tid] = W_b[tid];

    int w = tid >> 6, lane = tid & 63;
    int lo4 = lane & 15, hi4 = lane >> 4;
    const float* ab = a_buf + b * NN + ntile * 128 + w * 32;
    float a0 = ab[lo4], a1 = ab[16 + lo4];

    f32x4 acc00 = {0.f,0.f,0.f,0.f}, acc01 = {0.f,0.f,0.f,0.f};
    f32x4 acc10 = {0.f,0.f,0.f,0.f}, acc11 = {0.f,0.f,0.f,0.f};

    const uint4* pf4 = (const uint4*)psi_pk + (size_t)b * 4096;
    __syncthreads();

    uint4 p0a = pf4[lane],       p0b = pf4[64 + lane];
    uint4 p1a = pf4[128 + lane], p1b = pf4[192 + lane];
    for (int ks = 0; ks < 32; ks += 2) {
        uint4 n0a, n0b, n1a, n1b;
        bool more = (ks + 2 < 32);
        if (more) {
            n0a = pf4[(ks + 2) * 128 + lane]; n0b = pf4[(ks + 2) * 128 + 64 + lane];
            n1a = pf4[(ks + 3) * 128 + lane]; n1b = pf4[(ks + 3) * 128 + 64 + lane];
        }
        mfma_step(ks,     c_lds, hi4, a0, a1, p0a, p0b, acc00, acc01, acc10, acc11);
        mfma_step(ks + 1, c_lds, hi4, a0, a1, p1a, p1b, acc00, acc01, acc10, acc11);
        if (more) { p0a = n0a; p0b = n0b; p1a = n1a; p1b = n1b; }
    }

    const float inv = 1.0f / (float)MM;
    #pragma unroll
    for (int r = 0; r < 4; ++r) {
        yT[lo4 * 130 + w * 32 + hi4 * 4 + r]             = acc00[r] * inv;
        yT[(16 + lo4) * 130 + w * 32 + hi4 * 4 + r]      = acc01[r] * inv;
        yT[lo4 * 130 + w * 32 + 16 + hi4 * 4 + r]        = acc10[r] * inv;
        yT[(16 + lo4) * 130 + w * 32 + 16 + hi4 * 4 + r] = acc11[r] * inv;
    }
    __syncthreads();

    // output conv: 128 pixels x 64 o, thread = (pixel, o-half)
    int p = tid & 127, oh = tid >> 7;
    float yv[ICC];
    #pragma unroll
    for (int icx = 0; icx < ICC; ++icx) yv[icx] = yT[icx * 130 + p];
    float* wyp = wy + (size_t)b * CC * NN + ntile * 128 + p;
    #pragma unroll 4
    for (int od = 0; od < 32; ++od) {
        int o = oh * 32 + od;
        float s = Wb_lds[o];
        const float* wrow = &W_lds[o * ICC];
        #pragma unroll
        for (int icx = 0; icx < ICC; ++icx) s += wrow[icx] * yv[icx];
        wyp[o * NN] = s;
    }
}

// ---- K3: per-(b,o) partial BN sums -> atomics ----
__global__ void k_stats2(const float* __restrict__ wy, float* __restrict__ sumbuf) {
    int o = blockIdx.x & 63, b = blockIdx.x >> 6;
    int tid = threadIdx.x;
    const float4* p = (const float4*)(wy + ((size_t)(b * CC + o)) * NN);
    float s = 0.f, s2 = 0.f;
    #pragma unroll
    for (int i = 0; i < 4; ++i) {
        float4 v = p[tid + i * 256];
        s += v.x + v.y + v.z + v.w;
        s2 += v.x * v.x + v.y * v.y + v.z * v.z + v.w * v.w;
    }
    for (int off = 32; off >= 1; off >>= 1) {
        s += __shfl_xor(s, off, 64);
        s2 += __shfl_xor(s2, off, 64);
    }
    __shared__ float ws1[4], ws2[4];
    int wv = tid >> 6;
    if ((tid & 63) == 0) { ws1[wv] = s; ws2[wv] = s2; }
    __syncthreads();
    if (tid == 0) {
        atomicAdd(&sumbuf[o], ws1[0] + ws1[1] + ws1[2] + ws1[3]);
        atomicAdd(&sumbuf[CC + o], ws2[0] + ws2[1] + ws2[2] + ws2[3]);
    }
}

// ---- K4: finalize BN scale/shift ----
__global__ void k_bn(const float* __restrict__ sumbuf, const float* __restrict__ bn_gamma,
                     const float* __restrict__ bn_beta, float* __restrict__ scale_shift) {
    int o = threadIdx.x;
    if (o < CC) {
        float nN = (float)(BB * NN);
        float mean = sumbuf[o] / nN;
        float var = sumbuf[CC + o] / nN - mean * mean;
        float sc = bn_gamma[o] * rsqrtf(var + 1e-5f);
        scale_shift[o] = sc;
        scale_shift[CC + o] = bn_beta[o] - mean * sc;
    }
}

// ---- K5: normalize + residual (in-place on d_out) ----
__global__ void k_final(float* __restrict__ out, const float* __restrict__ x,
                        const float* __restrict__ scale_shift) {
    size_t i = (size_t)blockIdx.x * blockDim.x + threadIdx.x;
    size_t tot = (size_t)BB * CC * NN / 4;
    if (i < tot) {
        float4 w4 = ((const float4*)out)[i];
        float4 x4 = ((const float4*)x)[i];
        int o = (int)((i >> 10) & 63);
        float sc = scale_shift[o], sh = scale_shift[CC + o];
        float4 r;
        r.x = w4.x * sc + sh + x4.x;
        r.y = w4.y * sc + sh + x4.y;
        r.z = w4.z * sc + sh + x4.z;
        r.w = w4.w * sc + sh + x4.w;
        ((float4*)out)[i] = r;
    }
}

extern "C" void kernel_launch(void* const* d_in, const int* in_sizes, int n_in,
                              void* d_out, int out_size, void* d_ws, size_t ws_size,
                              hipStream_t stream) {
    const float* x        = (const float*)d_in[0];
    const float* psi_w    = (const float*)d_in[1];
    const float* psi_b    = (const float*)d_in[2];
    const float* theta_w  = (const float*)d_in[3];
    const float* theta_b  = (const float*)d_in[4];
    const float* phi_w    = (const float*)d_in[5];
    const float* phi_b    = (const float*)d_in[6];
    const float* concat_w = (const float*)d_in[7];
    const float* W_w      = (const float*)d_in[8];
    const float* W_b      = (const float*)d_in[9];
    const float* bn_gamma = (const float*)d_in[10];
    const float* bn_beta  = (const float*)d_in[11];

    float* ws = (float*)d_ws;
    float*    a_buf  = ws;                                  // 65536 floats
    float*    c_buf  = a_buf + BB * NN;                     // 16384
    unsigned* psi_pk = (unsigned*)(c_buf + BB * MM);        // 262144 uints, 16B-aligned
    float*    sumbuf = (float*)(psi_pk + BB * 16384);       // 128
    float*    sc_sh  = sumbuf + 128;                        // 128
    float*    wy     = (float*)d_out;                       // staged in output buffer

    k_pool<<<BB * 64, 256, 0, stream>>>(x, psi_w, psi_b, phi_w, phi_b,
                                        theta_w, theta_b, concat_w,
                                        psi_pk, c_buf, a_buf, sumbuf);
    k_attn<<<BB * 32, 256, 0, stream>>>(a_buf, c_buf, psi_pk, W_w, W_b, wy);
    k_stats2<<<BB * CC, 256, 0, stream>>>(wy, sumbuf);
    k_bn<<<1, 64, 0, stream>>>(sumbuf, bn_gamma, bn_beta, sc_sh);
    k_final<<<(BB * CC * NN / 4 + 255) / 256, 256, 0, stream>>>(wy, x, sc_sh);
}

// Round 9
// 135.953 us; speedup vs baseline: 2.4792x; 1.0324x over previous
//
#include <hip/hip_runtime.h>

#define BB 16
#define CC 64
#define ICC 32
#define NN 4096   // F*T
#define MM 1024   // 32*32

typedef __attribute__((ext_vector_type(8))) short short8;
typedef __attribute__((ext_vector_type(4))) float f32x4;

static __device__ __forceinline__ unsigned cvt_pk_bf16(float lo, float hi) {
    unsigned d;
    asm("v_cvt_pk_bf16_f32 %0, %1, %2" : "=v"(d) : "v"(lo), "v"(hi));
    return d;
}
static __device__ __forceinline__ short8 as_s8(uint4 u) {
    union { uint4 a; short8 b; } t; t.a = u; return t.b;
}
static __device__ __forceinline__ float bf16_to_f32(unsigned u) {
    return __uint_as_float(u << 16);
}

// ---- K1: psi/phi conv + 2x2 maxpool (thread-local m-pair) + a_buf + c_buf ----
__global__ void __launch_bounds__(256) k_pool(
        const float* __restrict__ x,
        const float* __restrict__ psi_w, const float* __restrict__ psi_b,
        const float* __restrict__ phi_w, const float* __restrict__ phi_b,
        const float* __restrict__ theta_w, const float* __restrict__ theta_b,
        const float* __restrict__ concat_w,
        unsigned* __restrict__ psi_pk, float* __restrict__ c_buf,
        float* __restrict__ a_buf, float* __restrict__ sumbuf) {
    __shared__ float pw[CC * ICC];   // [c][ic]
    __shared__ float fw[CC * ICC];
    __shared__ float vth[CC];
    __shared__ float xt[CC * 64];    // [c][row2][32]
    __shared__ float sconst;
    int tid = threadIdx.x;
    int b = blockIdx.x >> 6;
    int mtile = blockIdx.x & 63;     // 16 m-values per block
    int fp = mtile >> 1;             // pooled row (same for all 16 m)
    int tpb = (mtile & 1) * 16;      // pooled col base

    if (blockIdx.x == 0 && tid < 2 * CC) sumbuf[tid] = 0.f;
    for (int i = tid; i < CC * ICC; i += 256) {
        int ic = i >> 6, c = i & 63;
        pw[c * ICC + ic] = psi_w[i];
        fw[c * ICC + ic] = phi_w[i];
    }
    if (tid < CC) {
        float s = 0.f;
        for (int ic = 0; ic < ICC; ++ic) s += concat_w[ic] * theta_w[ic * CC + tid];
        vth[tid] = s;
    }
    if (tid == 255) {
        float s = 0.f;
        for (int ic = 0; ic < ICC; ++ic) s += concat_w[ic] * theta_b[ic];
        sconst = s;
    }
    // stage x tile: 64 c x 2 rows x 32 cols
    const float* xb = x + (size_t)b * CC * NN;
    for (int i = tid; i < 1024; i += 256) {
        int c = i >> 4, row = (i >> 3) & 1, jj = i & 7;
        float4 v = *(const float4*)(xb + c * NN + (2 * fp + row) * 64 + 2 * tpb + jj * 4);
        *(float4*)&xt[c * 64 + row * 32 + jj * 4] = v;
    }
    __syncthreads();

    int ic = tid & 31;
    int mp = tid >> 5;               // m-pair index 0..7 -> m0 = mtile*16 + 2*mp
    float p00=0,p01=0,p02=0,p03=0, p10=0,p11=0,p12=0,p13=0;
    float q00=0,q01=0,q02=0,q03=0, q10=0,q11=0,q12=0,q13=0;
    for (int c = 0; c < CC; ++c) {
        float4 r0 = *(const float4*)&xt[c * 64 + mp * 4];        // row 0, cols 4mp..4mp+3
        float4 r1 = *(const float4*)&xt[c * 64 + 32 + mp * 4];   // row 1
        float wp = pw[c * ICC + ic], wf = fw[c * ICC + ic];
        p00 += wp*r0.x; p01 += wp*r0.y; p02 += wp*r1.x; p03 += wp*r1.y;
        p10 += wp*r0.z; p11 += wp*r0.w; p12 += wp*r1.z; p13 += wp*r1.w;
        q00 += wf*r0.x; q01 += wf*r0.y; q02 += wf*r1.x; q03 += wf*r1.y;
        q10 += wf*r0.z; q11 += wf*r0.w; q12 += wf*r1.z; q13 += wf*r1.w;
    }
    float pb = psi_b[ic], fb = phi_b[ic];
    float psi0 = fmaxf(fmaxf(p00,p01),fmaxf(p02,p03)) + pb;
    float psi1 = fmaxf(fmaxf(p10,p11),fmaxf(p12,p13)) + pb;
    float phi0 = fmaxf(fmaxf(q00,q01),fmaxf(q02,q03)) + fb;
    float phi1 = fmaxf(fmaxf(q10,q11),fmaxf(q12,q13)) + fb;

    int m0 = mtile * 16 + 2 * mp;
    float wd0 = concat_w[2 * ICC], wd1 = concat_w[2 * ICC + 1];
    float wph = concat_w[ICC + ic];
    float v0 = wph * phi0, v1 = wph * phi1;
    for (int off = 16; off >= 1; off >>= 1) {
        v0 += __shfl_xor(v0, off, 32);
        v1 += __shfl_xor(v1, off, 32);
    }
    if (ic == 0) {
        int tp = tpb + 2 * mp;
        c_buf[b * MM + m0]     = v0 - (wd0 * (fp * (1.f/31.f)) + wd1 * (tp * (1.f/31.f)));
        c_buf[b * MM + m0 + 1] = v1 - (wd0 * (fp * (1.f/31.f)) + wd1 * ((tp + 1) * (1.f/31.f)));
    }
    // psi bf16 pair, MFMA-B fragment order (thread-local pack, no shfl)
    int mpg = mtile * 8 + mp;                 // global m-pair 0..511
    int ks = mpg >> 4, kg = (mpg >> 2) & 3, cidx = mpg & 3;
    psi_pk[b * 16384 + ks * 512 + (ic >> 4) * 256 + kg * 64 + (ic & 15) * 4 + cidx]
        = cvt_pk_bf16(psi0, psi1);

    // a_buf: 64 pixels per block, threads with ic<8
    if (ic < 8) {
        int pix = mp * 8 + ic;
        int row = pix >> 5, colo = pix & 31;
        float sa = 0.f;
        #pragma unroll 8
        for (int c = 0; c < CC; ++c) sa += vth[c] * xt[c * 64 + row * 32 + colo];
        int f = 2 * fp + row, t = 2 * tpb + colo;
        a_buf[b * NN + f * 64 + t] = sa + sconst + wd0 * (f * (1.f/63.f)) + wd1 * (t * (1.f/63.f));
    }
}

static __device__ __forceinline__ void mfma_step(
        int ks, const float* c_lds, int hi4, float a0, float a1,
        uint4 bu0, uint4 bu1,
        f32x4& acc00, f32x4& acc01, f32x4& acc10, f32x4& acc11) {
    float4 c0 = *(const float4*)&c_lds[ks * 32 + hi4 * 8];
    float4 c1 = *(const float4*)&c_lds[ks * 32 + hi4 * 8 + 4];
    uint4 up;
    up.x = cvt_pk_bf16(fmaxf(a0 + c0.x, 0.f), fmaxf(a0 + c0.y, 0.f));
    up.y = cvt_pk_bf16(fmaxf(a0 + c0.z, 0.f), fmaxf(a0 + c0.w, 0.f));
    up.z = cvt_pk_bf16(fmaxf(a0 + c1.x, 0.f), fmaxf(a0 + c1.y, 0.f));
    up.w = cvt_pk_bf16(fmaxf(a0 + c1.z, 0.f), fmaxf(a0 + c1.w, 0.f));
    short8 ua0 = as_s8(up);
    up.x = cvt_pk_bf16(fmaxf(a1 + c0.x, 0.f), fmaxf(a1 + c0.y, 0.f));
    up.y = cvt_pk_bf16(fmaxf(a1 + c0.z, 0.f), fmaxf(a1 + c0.w, 0.f));
    up.z = cvt_pk_bf16(fmaxf(a1 + c1.x, 0.f), fmaxf(a1 + c1.y, 0.f));
    up.w = cvt_pk_bf16(fmaxf(a1 + c1.z, 0.f), fmaxf(a1 + c1.w, 0.f));
    short8 ua1 = as_s8(up);
    short8 vb0 = as_s8(bu0), vb1 = as_s8(bu1);
    acc00 = __builtin_amdgcn_mfma_f32_16x16x32_bf16(ua0, vb0, acc00, 0, 0, 0);
    acc01 = __builtin_amdgcn_mfma_f32_16x16x32_bf16(ua0, vb1, acc01, 0, 0, 0);
    acc10 = __builtin_amdgcn_mfma_f32_16x16x32_bf16(ua1, vb0, acc10, 0, 0, 0);
    acc11 = __builtin_amdgcn_mfma_f32_16x16x32_bf16(ua1, vb1, acc11, 0, 0, 0);
}

// ---- K2: MFMA attention + output conv -> wy16 (bf16 staging) ----
__global__ void __launch_bounds__(256) k_attn(
        const float* __restrict__ a_buf, const float* __restrict__ c_buf,
        const unsigned* __restrict__ psi_pk,
        const float* __restrict__ W_w, const float* __restrict__ W_b,
        unsigned short* __restrict__ wy16) {
    __shared__ float c_lds[MM];          // 4 KB
    __shared__ float W_lds[CC * ICC];    // 8 KB [o][ic]
    __shared__ float Wb_lds[CC];
    __shared__ float yT[ICC * 130];      // transposed y, padded
    int tid = threadIdx.x;
    int b = blockIdx.x >> 5;
    int ntile = blockIdx.x & 31;         // 128 pixels per block
    for (int i = tid; i < MM; i += 256) c_lds[i] = c_buf[b * MM + i];
    for (int i = tid; i < CC * ICC; i += 256) W_lds[i] = W_w[(i >> 5) * (ICC + 1) + (i & 31)];
    if (tid < CC) Wb_lds[tid] = W_b[tid];

    int w = tid >> 6, lane = tid & 63;
    int lo4 = lane & 15, hi4 = lane >> 4;
    const float* ab = a_buf + b * NN + ntile * 128 + w * 32;
    float a0 = ab[lo4], a1 = ab[16 + lo4];

    f32x4 acc00 = {0.f,0.f,0.f,0.f}, acc01 = {0.f,0.f,0.f,0.f};
    f32x4 acc10 = {0.f,0.f,0.f,0.f}, acc11 = {0.f,0.f,0.f,0.f};

    const uint4* pf4 = (const uint4*)psi_pk + (size_t)b * 4096;
    __syncthreads();

    uint4 p0a = pf4[lane],       p0b = pf4[64 + lane];
    uint4 p1a = pf4[128 + lane], p1b = pf4[192 + lane];
    for (int ks = 0; ks < 32; ks += 2) {
        uint4 n0a, n0b, n1a, n1b;
        bool more = (ks + 2 < 32);
        if (more) {
            n0a = pf4[(ks + 2) * 128 + lane]; n0b = pf4[(ks + 2) * 128 + 64 + lane];
            n1a = pf4[(ks + 3) * 128 + lane]; n1b = pf4[(ks + 3) * 128 + 64 + lane];
        }
        mfma_step(ks,     c_lds, hi4, a0, a1, p0a, p0b, acc00, acc01, acc10, acc11);
        mfma_step(ks + 1, c_lds, hi4, a0, a1, p1a, p1b, acc00, acc01, acc10, acc11);
        if (more) { p0a = n0a; p0b = n0b; p1a = n1a; p1b = n1b; }
    }

    const float inv = 1.0f / (float)MM;
    #pragma unroll
    for (int r = 0; r < 4; ++r) {
        yT[lo4 * 130 + w * 32 + hi4 * 4 + r]             = acc00[r] * inv;
        yT[(16 + lo4) * 130 + w * 32 + hi4 * 4 + r]      = acc01[r] * inv;
        yT[lo4 * 130 + w * 32 + 16 + hi4 * 4 + r]        = acc10[r] * inv;
        yT[(16 + lo4) * 130 + w * 32 + 16 + hi4 * 4 + r] = acc11[r] * inv;
    }
    __syncthreads();

    // output conv: 128 pixels x 64 o, thread = (pixel, o-half); store bf16
    int p = tid & 127, oh = tid >> 7;
    float yv[ICC];
    #pragma unroll
    for (int icx = 0; icx < ICC; ++icx) yv[icx] = yT[icx * 130 + p];
    unsigned short* wyp = wy16 + (size_t)b * CC * NN + ntile * 128 + p;
    #pragma unroll 4
    for (int od = 0; od < 32; ++od) {
        int o = oh * 32 + od;
        float s = Wb_lds[o];
        const float* wrow = &W_lds[o * ICC];
        #pragma unroll
        for (int icx = 0; icx < ICC; ++icx) s += wrow[icx] * yv[icx];
        wyp[(size_t)o * NN] = (unsigned short)(cvt_pk_bf16(s, 0.f) & 0xffffu);
    }
}

// ---- K3: per-(b,o) partial BN sums from bf16 wy -> atomics ----
__global__ void k_stats2(const unsigned short* __restrict__ wy16, float* __restrict__ sumbuf) {
    int o = blockIdx.x & 63, b = blockIdx.x >> 6;
    int tid = threadIdx.x;
    const uint2* p = (const uint2*)(wy16 + ((size_t)(b * CC + o)) * NN);
    float s = 0.f, s2 = 0.f;
    #pragma unroll
    for (int i = 0; i < 4; ++i) {
        uint2 v = p[tid + i * 256];
        float f0 = bf16_to_f32(v.x & 0xffffu), f1 = bf16_to_f32(v.x >> 16);
        float f2 = bf16_to_f32(v.y & 0xffffu), f3 = bf16_to_f32(v.y >> 16);
        s  += f0 + f1 + f2 + f3;
        s2 += f0*f0 + f1*f1 + f2*f2 + f3*f3;
    }
    for (int off = 32; off >= 1; off >>= 1) {
        s += __shfl_xor(s, off, 64);
        s2 += __shfl_xor(s2, off, 64);
    }
    __shared__ float ws1[4], ws2[4];
    int wv = tid >> 6;
    if ((tid & 63) == 0) { ws1[wv] = s; ws2[wv] = s2; }
    __syncthreads();
    if (tid == 0) {
        atomicAdd(&sumbuf[o], ws1[0] + ws1[1] + ws1[2] + ws1[3]);
        atomicAdd(&sumbuf[CC + o], ws2[0] + ws2[1] + ws2[2] + ws2[3]);
    }
}

// ---- K4: BN finalize (per-block, o uniform) + normalize + residual ----
__global__ void __launch_bounds__(256) k_final(
        float* __restrict__ out, const float* __restrict__ x,
        const unsigned short* __restrict__ wy16,
        const float* __restrict__ sumbuf,
        const float* __restrict__ bn_gamma, const float* __restrict__ bn_beta) {
    __shared__ float s_sc, s_sh;
    size_t i = (size_t)blockIdx.x * 256 + threadIdx.x;   // float4 index
    int o = (int)((i >> 10) & 63);                       // uniform per block
    if (threadIdx.x == 0) {
        float nN = (float)(BB * NN);
        float mean = sumbuf[o] / nN;
        float var = sumbuf[CC + o] / nN - mean * mean;
        float sc = bn_gamma[o] * rsqrtf(var + 1e-5f);
        s_sc = sc;
        s_sh = bn_beta[o] - mean * sc;
    }
    __syncthreads();
    float sc = s_sc, sh = s_sh;
    uint2 wv = ((const uint2*)wy16)[i];
    float4 x4 = ((const float4*)x)[i];
    float4 r;
    r.x = bf16_to_f32(wv.x & 0xffffu) * sc + sh + x4.x;
    r.y = bf16_to_f32(wv.x >> 16)     * sc + sh + x4.y;
    r.z = bf16_to_f32(wv.y & 0xffffu) * sc + sh + x4.z;
    r.w = bf16_to_f32(wv.y >> 16)     * sc + sh + x4.w;
    ((float4*)out)[i] = r;
}

extern "C" void kernel_launch(void* const* d_in, const int* in_sizes, int n_in,
                              void* d_out, int out_size, void* d_ws, size_t ws_size,
                              hipStream_t stream) {
    const float* x        = (const float*)d_in[0];
    const float* psi_w    = (const float*)d_in[1];
    const float* psi_b    = (const float*)d_in[2];
    const float* theta_w  = (const float*)d_in[3];
    const float* theta_b  = (const float*)d_in[4];
    const float* phi_w    = (const float*)d_in[5];
    const float* phi_b    = (const float*)d_in[6];
    const float* concat_w = (const float*)d_in[7];
    const float* W_w      = (const float*)d_in[8];
    const float* W_b      = (const float*)d_in[9];
    const float* bn_gamma = (const float*)d_in[10];
    const float* bn_beta  = (const float*)d_in[11];

    float* ws = (float*)d_ws;
    float*          a_buf  = ws;                              // 65536 floats
    float*          c_buf  = a_buf + BB * NN;                 // 16384
    unsigned*       psi_pk = (unsigned*)(c_buf + BB * MM);    // 262144 uints
    float*          sumbuf = (float*)(psi_pk + BB * 16384);   // 128
    unsigned short* wy16   = (unsigned short*)(ws + 344320);  // BB*CC*NN ushorts (8.4MB), 16B-aligned
    float*          out    = (float*)d_out;

    k_pool<<<BB * 64, 256, 0, stream>>>(x, psi_w, psi_b, phi_w, phi_b,
                                        theta_w, theta_b, concat_w,
                                        psi_pk, c_buf, a_buf, sumbuf);
    k_attn<<<BB * 32, 256, 0, stream>>>(a_buf, c_buf, psi_pk, W_w, W_b, wy16);
    k_stats2<<<BB * CC, 256, 0, stream>>>(wy16, sumbuf);
    k_final<<<BB * CC * NN / 1024, 256, 0, stream>>>(out, x, wy16, sumbuf, bn_gamma, bn_beta);
}